// Round 9
// baseline (1407.253 us; speedup 1.0000x reference)
//
#include <hip/hip_runtime.h>
#include <hip/hip_bf16.h>
#include <math.h>

// DeepGESN: 2 layers of h = tanh(wiu + L @ (h @ W_hh^T)), 10 iters each.
// Rewrite: L@(h@W) == (L@h)@W. G=L@h in bf16 MFMA with two-term split
// (L=Lhi+Llo, h=hhi+hlo, 3 products; measured absmax 0.0093 vs 0.02 thr).
//
// R9: persistent kernel, spill-free. R7's skeleton (grid barrier, phase
// fns) + R6's mm partition (block = 128-row panel x 1/8 K, B-slice in LDS,
// Gp + 8-way reduce in post -> bit-identical numerics). A is STREAMED
// per-kbl (R7 lesson: hoarding A in VGPRs spills at the 128-reg cap).
// unroll 4 pins in-flight A-loads (8 x 16B) so live set stays ~110 regs.
//
// Pack layouts (lane-linear dwordx4 fragment loads):
//  Apack[rb][kb][l][8]: val = L[rb*16 + (l&15)][kb*32 + 8*(l>>4) + j]
//  Bpack[kb][cf][l][8]: val = h[kb*32 + 8*(l>>4) + j][cf*16 + (l&15)]
// mfma_f32_16x16x32_bf16: D[(l>>4)*4+r][l&15] (m89/m91 layout).

#define NN 4096
#define HH 64
#define NBLK 256
#define TPB 512

typedef float  f32x4  __attribute__((ext_vector_type(4)));
typedef short  bf16x8 __attribute__((ext_vector_type(8)));

static __device__ __forceinline__ unsigned short bf16_bits(__hip_bfloat16 b) {
    union { __hip_bfloat16 b; unsigned short u; } cv; cv.b = b; return cv.u;
}

// ---------------------------------------------------------------------------
// Split + pack L -> Ahi/Alo (bf16 fragment-linear, 32MB each)
// ---------------------------------------------------------------------------
__global__ __launch_bounds__(256) void convert_L(
    const float* __restrict__ L, short* __restrict__ Ahi, short* __restrict__ Alo)
{
    __shared__ float T[16 * 132];
    const int t  = threadIdx.x;
    const int rb = blockIdx.x >> 5;
    const int kg = blockIdx.x & 31;

    {
        const int row = t >> 4;
        const int c4  = (t & 15) * 4;
        const float* src = L + (size_t)(rb * 16 + row) * NN + kg * 128;
        float4 v0 = *reinterpret_cast<const float4*>(src + c4);
        float4 v1 = *reinterpret_cast<const float4*>(src + c4 + 64);
        *reinterpret_cast<float4*>(&T[row * 132 + c4])      = v0;
        *reinterpret_cast<float4*>(&T[row * 132 + c4 + 64]) = v1;
    }
    __syncthreads();

    const int kbl = t >> 6;
    const int l   = t & 63;
    const int r   = l & 15, g = l >> 4;
    short hi8[8], lo8[8];
#pragma unroll
    for (int j = 0; j < 8; ++j) {
        const float v = T[r * 132 + kbl * 32 + g * 8 + j];
        __hip_bfloat16 bh = __float2bfloat16(v);
        const float vh = __bfloat162float(bh);
        __hip_bfloat16 bl = __float2bfloat16(v - vh);
        hi8[j] = (short)bf16_bits(bh);
        lo8[j] = (short)bf16_bits(bl);
    }
    const size_t off = ((size_t)(rb * 128 + kg * 4 + kbl) * 64 + l) * 8;
    *reinterpret_cast<bf16x8*>(Ahi + off) = *reinterpret_cast<bf16x8*>(hi8);
    *reinterpret_cast<bf16x8*>(Alo + off) = *reinterpret_cast<bf16x8*>(lo8);
}

// ---------------------------------------------------------------------------
// Device-scope grid barrier (sense-reversing). 256 blocks co-resident by
// construction (128KB LDS -> 1 block/CU). Verified correct in R7.
// ---------------------------------------------------------------------------
__device__ __forceinline__ void grid_barrier(unsigned* cnt, unsigned* gen, int nb)
{
    __syncthreads();
    if (threadIdx.x == 0) {
        __threadfence();
        unsigned g = __hip_atomic_load(gen, __ATOMIC_RELAXED,
                                       __HIP_MEMORY_SCOPE_AGENT);
        unsigned old = __hip_atomic_fetch_add(cnt, 1u, __ATOMIC_ACQ_REL,
                                              __HIP_MEMORY_SCOPE_AGENT);
        if (old == (unsigned)(nb - 1)) {
            __hip_atomic_store(cnt, 0u, __ATOMIC_RELAXED,
                               __HIP_MEMORY_SCOPE_AGENT);
            __hip_atomic_fetch_add(gen, 1u, __ATOMIC_RELEASE,
                                   __HIP_MEMORY_SCOPE_AGENT);
        } else {
            while (__hip_atomic_load(gen, __ATOMIC_ACQUIRE,
                                     __HIP_MEMORY_SCOPE_AGENT) == g) {
                __builtin_amdgcn_s_sleep(2);
            }
        }
        __threadfence();
    }
    __syncthreads();
}

// ---------------------------------------------------------------------------
// Post phase: z = (wiu_in?) + (reduce_s Gsrc) @ W^T ; h = tanh(z);
// writes hf32, B-pack, optional out2/wiu_out. nsplit==0: Gsrc is x.
// ---------------------------------------------------------------------------
__device__ __forceinline__ void post_phase(
    const float* __restrict__ Gsrc, int nsplit,
    const float* __restrict__ wiu_in, float* __restrict__ wiu_out,
    const float* __restrict__ W, float* __restrict__ hf32,
    short* __restrict__ Bhi, short* __restrict__ Blo,
    float* __restrict__ out2, int outc0, int r0, char* smem)
{
    float* W_lds = (float*)smem;                              // 64*65 f32
    float* G_lds = (float*)(smem + 16640);                    // 16*68 f32
    unsigned short* Hi_lds = (unsigned short*)(smem + 16640 + 4352);
    unsigned short* Lo_lds = (unsigned short*)(smem + 16640 + 4352 + 2112);
    const int t = threadIdx.x;

    {   // W load: 512 thr x 8 elems
        const int j  = t >> 3;
        const int k0 = (t & 7) * 8;
#pragma unroll
        for (int q = 0; q < 8; ++q)
            W_lds[j * 65 + k0 + q] = W[j * 64 + k0 + q];
    }
    if (t < 256) {  // load(+reduce) G: 16x64 f32 = 256 float4
        const int row = t >> 4;
        const int c4  = (t & 15) * 4;
        float4 sum;
        if (nsplit == 0) {
            sum = *reinterpret_cast<const float4*>(
                Gsrc + (size_t)(r0 + row) * HH + c4);
        } else {
            sum = make_float4(0.f, 0.f, 0.f, 0.f);
            for (int sidx = 0; sidx < nsplit; ++sidx) {
                const float4 v = *reinterpret_cast<const float4*>(
                    Gsrc + (size_t)sidx * NN * HH + (size_t)(r0 + row) * HH + c4);
                sum.x += v.x; sum.y += v.y; sum.z += v.z; sum.w += v.w;
            }
        }
        *reinterpret_cast<float4*>(&G_lds[row * 68 + c4]) = sum;
    }
    __syncthreads();

    const int j  = t & 63;
    const int ig = t >> 6;
#pragma unroll
    for (int rr = 0; rr < 2; ++rr) {
        const int i = ig * 2 + rr;      // 0..15
        float z = wiu_in ? wiu_in[(size_t)(r0 + i) * HH + j] : 0.f;
#pragma unroll
        for (int m = 0; m < 64; ++m)
            z = fmaf(G_lds[i * 68 + m], W_lds[j * 65 + m], z);
        if (wiu_out) wiu_out[(size_t)(r0 + i) * HH + j] = z;
        const float hv = tanhf(z);
        hf32[(size_t)(r0 + i) * HH + j] = hv;
        if (out2) out2[(size_t)(r0 + i) * 128 + outc0 + j] = hv;
        __hip_bfloat16 bh = __float2bfloat16(hv);
        const float vh = __bfloat162float(bh);
        __hip_bfloat16 bl = __float2bfloat16(hv - vh);
        Hi_lds[i * 66 + j] = bf16_bits(bh);
        Lo_lds[i * 66 + j] = bf16_bits(bl);
    }
    __syncthreads();

    if (t < 128) {  // pack: 8 consecutive rows per thread at one column
        const int j2     = t & 63;
        const int glocal = t >> 6;
        const int kb     = r0 >> 5;
        const int gg     = ((r0 & 31) >> 3) + glocal;
        const int cf     = j2 >> 4;
        const int lane   = gg * 16 + (j2 & 15);
        short hi8[8], lo8[8];
#pragma unroll
        for (int jj = 0; jj < 8; ++jj) {
            const int i = glocal * 8 + jj;
            hi8[jj] = (short)Hi_lds[i * 66 + j2];
            lo8[jj] = (short)Lo_lds[i * 66 + j2];
        }
        const size_t off = ((size_t)(kb * 4 + cf) * 64 + lane) * 8;
        *reinterpret_cast<bf16x8*>(Bhi + off) = *reinterpret_cast<bf16x8*>(hi8);
        *reinterpret_cast<bf16x8*>(Blo + off) = *reinterpret_cast<bf16x8*>(lo8);
    }
}

// ---------------------------------------------------------------------------
// Persistent kernel. Block b mm-role: p=b>>3 row-panel, s=b&7 K-split,
// wave w -> rowblock p*8+w, K-chunk kb0=s*16 (== R6 partition, identical
// summation order). Post-role: rows b*16.
// ---------------------------------------------------------------------------
__global__ __launch_bounds__(TPB) void gesn_persistent(
    const short* __restrict__ Ahi, const short* __restrict__ Alo,
    short* __restrict__ Bhi, short* __restrict__ Blo,
    const float* __restrict__ X,
    const float* __restrict__ Wih0, const float* __restrict__ Whh0,
    const float* __restrict__ Wih1, const float* __restrict__ Whh1,
    float* __restrict__ wiu, float* __restrict__ hA, float* __restrict__ hB,
    float* __restrict__ Gp, float* __restrict__ out,
    unsigned* bar_cnt, unsigned* bar_gen)
{
    __shared__ char smem[131072];      // 128KB arena -> 1 block/CU
    const int t = threadIdx.x;
    const int b = blockIdx.x;
    const int w = t >> 6, l = t & 63;
    const int p = b >> 3, s = b & 7;
    const int rb  = p * 8 + w;
    const int kb0 = s * 16;
    const int r0  = b * 16;

    short* Bh_lds = (short*)smem;            // 64KB [kbl][cf][l][8]
    short* Bl_lds = (short*)(smem + 65536);  // 64KB

    for (int layer = 0; layer < 2; ++layer) {
        const float* x   = layer ? hA : X;
        const float* Wih = layer ? Wih1 : Wih0;
        const float* Whh = layer ? Whh1 : Whh0;
        float* hcur      = layer ? hB : hA;

        post_phase(x, 0, nullptr, wiu, Wih, hcur, Bhi, Blo, nullptr, 0, r0, smem);
        grid_barrier(bar_cnt, bar_gen, NBLK);

        for (int it = 0; it < 9; ++it) {
            // ---- mm phase: Gp[s] = partial (L@h), B-slice via LDS ----
            {
                const short* srcH = Bhi + (size_t)kb0 * 4 * 64 * 8;
                const short* srcL = Blo + (size_t)kb0 * 4 * 64 * 8;
#pragma unroll
                for (int q = 0; q < 8; ++q) {
                    const int idx = (q * 512 + t) * 8;
                    *reinterpret_cast<bf16x8*>(&Bh_lds[idx]) =
                        *reinterpret_cast<const bf16x8*>(srcH + idx);
                    *reinterpret_cast<bf16x8*>(&Bl_lds[idx]) =
                        *reinterpret_cast<const bf16x8*>(srcL + idx);
                }
            }
            __syncthreads();

            const size_t abase = ((size_t)(rb * 128 + kb0) * 64 + l) * 8;
            f32x4 accP[4] = {};        // aH*bH
            f32x4 accQ[4] = {};        // aH*bL + aL*bH
#pragma unroll 4
            for (int kbl = 0; kbl < 16; ++kbl) {
                const bf16x8 a_hi = *reinterpret_cast<const bf16x8*>(
                    Ahi + abase + (size_t)kbl * 512);
                const bf16x8 a_lo = *reinterpret_cast<const bf16x8*>(
                    Alo + abase + (size_t)kbl * 512);
                bf16x8 bH[4], bL[4];
#pragma unroll
                for (int cf = 0; cf < 4; ++cf) {
                    const int idx = ((kbl * 4 + cf) * 64 + l) * 8;
                    bH[cf] = *reinterpret_cast<const bf16x8*>(&Bh_lds[idx]);
                    bL[cf] = *reinterpret_cast<const bf16x8*>(&Bl_lds[idx]);
                }
#pragma unroll
                for (int cf = 0; cf < 4; ++cf) {
                    accP[cf] = __builtin_amdgcn_mfma_f32_16x16x32_bf16(
                        a_hi, bH[cf], accP[cf], 0, 0, 0);
                    accQ[cf] = __builtin_amdgcn_mfma_f32_16x16x32_bf16(
                        a_hi, bL[cf], accQ[cf], 0, 0, 0);
                    accQ[cf] = __builtin_amdgcn_mfma_f32_16x16x32_bf16(
                        a_lo, bH[cf], accQ[cf], 0, 0, 0);
                }
            }
            {
                float* g = Gp + (size_t)s * NN * HH;
                const int col0  = l & 15;
                const int rbase = (l >> 4) * 4;
#pragma unroll
                for (int cf = 0; cf < 4; ++cf)
#pragma unroll
                    for (int r = 0; r < 4; ++r)
                        g[(size_t)(rb * 16 + rbase + r) * HH + cf * 16 + col0]
                            = accP[cf][r] + accQ[cf][r];
            }
            grid_barrier(bar_cnt, bar_gen, NBLK);    // Gp ready

            float* o2 = (it == 8) ? out : nullptr;
            post_phase(Gp, 8, wiu, nullptr, Whh, hcur, Bhi, Blo,
                       o2, layer * 64, r0, smem);
            grid_barrier(bar_cnt, bar_gen, NBLK);    // h/B-pack ready
        }
    }
}

// ---------------------------------------------------------------------------
// Fallback f32 path (round-0 kernels, small-ws safety)
// ---------------------------------------------------------------------------
__global__ __launch_bounds__(256) void gesn_input_kernel(
    const float* __restrict__ x, const float* __restrict__ W,
    float* __restrict__ wiu, float* __restrict__ h)
{
    __shared__ float W_lds[64 * 65];
    __shared__ float x_lds[256];
    const int t = threadIdx.x;
    {
        const int j  = t >> 2;
        const int k0 = (t & 3) << 4;
#pragma unroll
        for (int q = 0; q < 16; ++q)
            W_lds[j * 65 + k0 + q] = W[j * 64 + k0 + q];
    }
    const int i0 = blockIdx.x * 4;
    x_lds[t] = x[i0 * 64 + t];
    __syncthreads();
    const int j = t & 63, i = t >> 6;
    float z = 0.f;
#pragma unroll
    for (int k = 0; k < 64; ++k)
        z = fmaf(x_lds[i * 64 + k], W_lds[j * 65 + k], z);
    const int gidx = (i0 + i) * 64 + j;
    wiu[gidx] = z;
    h[gidx]   = tanhf(z);
}

__global__ __launch_bounds__(256) void gesn_iter_kernel(
    const float* __restrict__ L, const float* __restrict__ h_in,
    const float* __restrict__ wiu, const float* __restrict__ W,
    float* __restrict__ h_out, float* __restrict__ out2, int out_col0)
{
    __shared__ float h_lds[64 * 64];
    __shared__ float L_lds[16 * 68];
    __shared__ float G_lds[16 * 68];
    __shared__ float W_lds[64 * 65];
    const int t = threadIdx.x;
    {
        const int j  = t >> 2;
        const int k0 = (t & 3) << 4;
#pragma unroll
        for (int q = 0; q < 16; ++q)
            W_lds[j * 65 + k0 + q] = W[j * 64 + k0 + q];
    }
    const int r0 = blockIdx.x * 16;
    const int p  = t >> 5;
    const int c0 = (t & 31) * 2;
    float acc00 = 0.f, acc01 = 0.f, acc10 = 0.f, acc11 = 0.f;
    const int lr = t >> 4;
    const int lc = (t & 15) * 4;
    for (int kb = 0; kb < 64; ++kb) {
        __syncthreads();
        const float4 lv = *reinterpret_cast<const float4*>(
            &L[(size_t)(r0 + lr) * 4096 + kb * 64 + lc]);
        *reinterpret_cast<float4*>(&L_lds[lr * 68 + lc]) = lv;
        const float4* hsrc = reinterpret_cast<const float4*>(h_in + kb * 4096);
        float4* hdst = reinterpret_cast<float4*>(h_lds);
#pragma unroll
        for (int q = 0; q < 4; ++q)
            hdst[t + 256 * q] = hsrc[t + 256 * q];
        __syncthreads();
#pragma unroll
        for (int kk = 0; kk < 64; ++kk) {
            const float  lv0 = L_lds[(2 * p) * 68 + kk];
            const float  lv1 = L_lds[(2 * p + 1) * 68 + kk];
            const float2 hv  = *reinterpret_cast<const float2*>(&h_lds[kk * 64 + c0]);
            acc00 = fmaf(lv0, hv.x, acc00);
            acc01 = fmaf(lv0, hv.y, acc01);
            acc10 = fmaf(lv1, hv.x, acc10);
            acc11 = fmaf(lv1, hv.y, acc11);
        }
    }
    G_lds[(2 * p) * 68 + c0]         = acc00;
    G_lds[(2 * p) * 68 + c0 + 1]     = acc01;
    G_lds[(2 * p + 1) * 68 + c0]     = acc10;
    G_lds[(2 * p + 1) * 68 + c0 + 1] = acc11;
    __syncthreads();
    const int j  = t & 63;
    const int iw = t >> 6;
#pragma unroll
    for (int rr = 0; rr < 4; ++rr) {
        const int i = iw * 4 + rr;
        float z = wiu[(size_t)(r0 + i) * 64 + j];
#pragma unroll
        for (int m = 0; m < 64; ++m)
            z = fmaf(G_lds[i * 68 + m], W_lds[j * 65 + m], z);
        const float hv = tanhf(z);
        h_out[(size_t)(r0 + i) * 64 + j] = hv;
        if (out2) out2[(size_t)(r0 + i) * 128 + out_col0 + j] = hv;
    }
}

// ---------------------------------------------------------------------------
extern "C" void kernel_launch(void* const* d_in, const int* in_sizes, int n_in,
                              void* d_out, int out_size, void* d_ws, size_t ws_size,
                              hipStream_t stream) {
    const float* X    = (const float*)d_in[0];
    const float* L    = (const float*)d_in[1];
    const float* Wih0 = (const float*)d_in[2];
    const float* Whh0 = (const float*)d_in[3];
    const float* Wih1 = (const float*)d_in[4];
    const float* Whh1 = (const float*)d_in[5];
    float* out = (float*)d_out;
    char* ws = (char*)d_ws;

    const size_t MB = 1024 * 1024;
    const size_t need = 77 * MB;

    if (ws_size >= need) {
        short* Ahi = (short*)(ws);                 // 32 MB
        short* Alo = (short*)(ws + 32 * MB);       // 32 MB
        short* Bhi = (short*)(ws + 64 * MB);       // 0.5 MB
        short* Blo = (short*)(ws + 64 * MB + 512 * 1024);
        float* wiu = (float*)(ws + 65 * MB);       // 1 MB
        float* hA  = (float*)(ws + 66 * MB);       // 1 MB
        float* hB  = (float*)(ws + 67 * MB);       // 1 MB
        float* Gp  = (float*)(ws + 68 * MB);       // 8 MB
        unsigned char* bar = (unsigned char*)(ws + 76 * MB);

        hipMemsetAsync(bar, 0, 1024, stream);      // barrier cnt+gen = 0
        convert_L<<<8192, 256, 0, stream>>>(L, Ahi, Alo);
        gesn_persistent<<<NBLK, TPB, 0, stream>>>(
            Ahi, Alo, Bhi, Blo, X, Wih0, Whh0, Wih1, Whh1,
            wiu, hA, hB, Gp, out,
            (unsigned*)bar, (unsigned*)(bar + 256));
    } else {
        // f32 fallback (verified round-0 path)
        float* wiu = (float*)(ws);
        float* hA  = (float*)(ws + (1u << 20));
        float* hB  = (float*)(ws + (2u << 20));
        for (int layer = 0; layer < 2; ++layer) {
            const float* x   = layer ? hB : X;
            const float* Wih = layer ? Wih1 : Wih0;
            const float* Whh = layer ? Whh1 : Whh0;
            gesn_input_kernel<<<1024, 256, 0, stream>>>(x, Wih, wiu, hA);
            float* cur = hA;
            float* nxt = hB;
            for (int it = 0; it < 9; ++it) {
                float* o2 = (it == 8) ? out : nullptr;
                gesn_iter_kernel<<<256, 256, 0, stream>>>(L, cur, wiu, Whh, nxt,
                                                          o2, layer * 64);
                float* tmp = cur; cur = nxt; nxt = tmp;
            }
        }
    }
}